// Round 1
// baseline (16.501 us; speedup 1.0000x reference)
//
#include <hip/hip_runtime.h>

#define N_ROWS 1048576

__global__ __launch_bounds__(256) void wos_kernel(
    const float2* __restrict__ x,        // [N] rows of 2 floats
    const float* __restrict__ biases,    // [4]
    const float* __restrict__ weights,   // [4]
    const float* __restrict__ threshold, // [1]
    float* __restrict__ out,             // [N]
    int n)
{
    int i = blockIdx.x * blockDim.x + threadIdx.x;
    if (i >= n) return;

    // Small params — L2/L3 cached broadcast loads, negligible.
    const float b0 = biases[0], b1 = biases[1], b2 = biases[2], b3 = biases[3];
    const float w0 = weights[0], w1 = weights[1], w2 = weights[2], w3 = weights[3];
    const float thr = threshold[0];

    const float2 xv = x[i];

    // lsb = concat([x, -x]) + biases ; integer-valued
    // vi = int32(lsb) + 128  (may be negative; arithmetic >> matches JAX)
    int vi[4];
    vi[0] = (int)(xv.x + b0) + 128;
    vi[1] = (int)(xv.y + b1) + 128;
    vi[2] = (int)(-xv.x + b2) + 128;
    vi[3] = (int)(-xv.y + b3) + 128;

    const float w[4] = {w0, w1, w2, w3};
    float inp[4] = {0.f, 0.f, 0.f, 0.f};
    bool active[4] = {true, true, true, true};
    int outv = 0;

#pragma unroll
    for (int k = 0; k < 8; ++k) {
        const int sh = 7 - k;
        float bit[4];
#pragma unroll
        for (int j = 0; j < 4; ++j) {
            bit[j] = (float)((vi[j] >> sh) & 1);
            if (active[j]) inp[j] = bit[j];
        }
        float wsum = 0.f;
#pragma unroll
        for (int j = 0; j < 4; ++j) wsum += (inp[j] > 0.f) ? w[j] : 0.f;
        const bool ob = (wsum >= thr);
        const float out_bit = ob ? 1.f : 0.f;
        outv += (ob ? 1 : 0) << sh;
#pragma unroll
        for (int j = 0; j < 4; ++j) {
            if (active[j] && bit[j] != out_bit) active[j] = false;
        }
    }

    out[i] = (float)(outv - 128);
}

extern "C" void kernel_launch(void* const* d_in, const int* in_sizes, int n_in,
                              void* d_out, int out_size, void* d_ws, size_t ws_size,
                              hipStream_t stream)
{
    const float2* x       = (const float2*)d_in[0];  // [N, 2] row-major
    const float* biases   = (const float*)d_in[1];   // [4]
    const float* weights  = (const float*)d_in[2];   // [4]
    const float* thresh   = (const float*)d_in[3];   // [1]
    float* out            = (float*)d_out;           // [N]

    const int n = in_sizes[0] / 2;                   // rows
    const int block = 256;
    const int grid = (n + block - 1) / block;
    wos_kernel<<<grid, block, 0, stream>>>(x, biases, weights, thresh, out, n);
}

// Round 2
// 10.534 us; speedup vs baseline: 1.5665x; 1.5665x over previous
//
#include <hip/hip_runtime.h>

// WOS bit-serial classifier, 4 rows per thread.
// Semantics: lsb = [x0,x1,-x0,-x1]+biases; vi = int(lsb)+128;
// 8 MSB-first steps: active lanes track current bit; ob = (sum_{bit==1} w >= thr);
// lanes freeze when their bit != ob; out = sum ob<<k - 128.
__global__ __launch_bounds__(256) void wos_kernel(
    const float4* __restrict__ x4,       // [Nrows/2] — each float4 = 2 rows
    const float* __restrict__ biases,    // [4]
    const float* __restrict__ weights,   // [4]
    const float* __restrict__ threshold, // [1]
    float4* __restrict__ out4,           // [Nrows/4]
    int nquads)
{
    int i = blockIdx.x * blockDim.x + threadIdx.x;
    if (i >= nquads) return;

    const float b0 = biases[0], b1 = biases[1], b2 = biases[2], b3 = biases[3];
    const float w0 = weights[0], w1 = weights[1], w2 = weights[2], w3 = weights[3];
    const float thr = threshold[0];

    // 16-entry LUT: bit m = (sum of weights for lanes set in m) >= thr.
    // Uniform across threads (scalar operands) — compiler keeps it in SGPR-ish path.
    const float s01[4] = {0.f, w0, w1, w0 + w1};
    const float s23[4] = {0.f, w2, w3, w2 + w3};
    int lut = 0;
#pragma unroll
    for (int m2 = 0; m2 < 4; ++m2)
#pragma unroll
        for (int m1 = 0; m1 < 4; ++m1)
            lut |= (int)(s01[m1] + s23[m2] >= thr) << (m2 * 4 + m1);

    const float4 a = x4[2 * i];
    const float4 c = x4[2 * i + 1];
    const float xs[4][2] = {{a.x, a.y}, {a.z, a.w}, {c.x, c.y}, {c.z, c.w}};

    float res[4];
#pragma unroll
    for (int r = 0; r < 4; ++r) {
        // vi may lie outside [0,255] (e.g. -x-64 down to -191+128=-63); for
        // sh in [0,7], (vi>>sh)&1 depends only on the low byte, so &0xFF is exact.
        const int v0 = (int)(xs[r][0] + b0) + 128;
        const int v1 = (int)(xs[r][1] + b1) + 128;
        const int v2 = (int)(-xs[r][0] + b2) + 128;
        const int v3 = (int)(-xs[r][1] + b3) + 128;
        const unsigned P = (unsigned)(v0 & 0xFF) | ((unsigned)(v1 & 0xFF) << 8) |
                           ((unsigned)(v2 & 0xFF) << 16) | ((unsigned)(v3 & 0xFF) << 24);

        int inp = 0, act = 0xF, outv = 0;
#pragma unroll
        for (int k = 7; k >= 0; --k) {
            // gather bit k of each byte into a 4-bit nibble
            const int nib = (int)(((((P >> k) & 0x01010101u) * 0x01020408u) >> 24) & 0xFu);
            inp = (nib & act) | (inp & ~act);      // active lanes track current bit
            const int ob = (lut >> inp) & 1;       // wsum >= thr via LUT
            outv |= ob << k;
            act &= ~(nib ^ (-ob & 0xF));           // freeze diverging lanes
        }
        res[r] = (float)(outv - 128);
    }
    out4[i] = make_float4(res[0], res[1], res[2], res[3]);
}

extern "C" void kernel_launch(void* const* d_in, const int* in_sizes, int n_in,
                              void* d_out, int out_size, void* d_ws, size_t ws_size,
                              hipStream_t stream)
{
    const float4* x4      = (const float4*)d_in[0];  // [N,2] rows, 2 rows per float4
    const float* biases   = (const float*)d_in[1];
    const float* weights  = (const float*)d_in[2];
    const float* thresh   = (const float*)d_in[3];
    float4* out4          = (float4*)d_out;

    const int nrows  = in_sizes[0] / 2;
    const int nquads = nrows / 4;                    // N=1048576 -> exact
    const int block  = 256;
    const int grid   = (nquads + block - 1) / block;
    wos_kernel<<<grid, block, 0, stream>>>(x4, biases, weights, thresh, out4, nquads);
}